// Round 9
// baseline (356.299 us; speedup 1.0000x reference)
//
#include <hip/hip_runtime.h>
#include <hip/hip_bf16.h>

#define TPB 256
#define SH 6
#define BW 64  // nodes per bucket = 1<<SH; NBUK must be <= 1024 (N <= 65536)

typedef unsigned short u16;

// bf16 helpers: payload stored as bf16 (halves gather BW), accumulate in fp32.
__device__ __forceinline__ u16 f_to_bf(float f) {
    unsigned u = __float_as_uint(f);
    return (u16)((u + 0x7fff + ((u >> 16) & 1)) >> 16);  // RNE
}
__device__ __forceinline__ float4 bf4_to_f4(ushort4 v) {
    float4 r;
    r.x = __uint_as_float((unsigned)v.x << 16);
    r.y = __uint_as_float((unsigned)v.y << 16);
    r.z = __uint_as_float((unsigned)v.z << 16);
    r.w = __uint_as_float((unsigned)v.w << 16);
    return r;
}

// ---------------- bucketed CSR build ----------------

__global__ void bucket_count_kernel(const int* __restrict__ dst0, const int* __restrict__ dst1,
                                    int E, int* __restrict__ bcnt, int nbuk) {
    const int* dst = blockIdx.y ? dst1 : dst0;
    int* bc = bcnt + blockIdx.y * 1024;
    __shared__ int hist[1024];
    for (int t = threadIdx.x; t < 1024; t += TPB) hist[t] = 0;
    __syncthreads();
    int base = blockIdx.x * 8192;
    int end = min(base + 8192, E);
    for (int e = base + (int)threadIdx.x; e < end; e += TPB)
        atomicAdd(&hist[dst[e] >> SH], 1);
    __syncthreads();
    for (int t = threadIdx.x; t < nbuk; t += TPB) {
        int h = hist[t];
        if (h) atomicAdd(&bc[t], h);
    }
}

__global__ void bucket_scan_kernel(const int* __restrict__ bcnt, int nbuk,
                                   int* __restrict__ boff, int* __restrict__ bcur) {
    int g = blockIdx.x;
    const int* bc = bcnt + g * 1024;
    int* bo = boff + g * 1024;
    int* bu = bcur + g * 1024;
    __shared__ int s[1024];
    int t = threadIdx.x;
    int v = (t < nbuk) ? bc[t] : 0;
    s[t] = v;
    __syncthreads();
    for (int st = 1; st < 1024; st <<= 1) {
        int u = (t >= st) ? s[t - st] : 0;
        __syncthreads();
        s[t] += u;
        __syncthreads();
    }
    if (t < nbuk) { int e = s[t] - v; bo[t] = e; bu[t] = e; }
}

__global__ void bucket_scatter_kernel(const int* __restrict__ e0, const int* __restrict__ e1,
                                      int E, int* __restrict__ bcur,
                                      int* __restrict__ ebuf0, int* __restrict__ ebuf1, int nbuk) {
    int g = blockIdx.y;
    const int* src = g ? e1 : e0;
    const int* dst = src + E;
    int* ebuf = g ? ebuf1 : ebuf0;
    int* bu = bcur + g * 1024;
    __shared__ int hist[1024];
    for (int t = threadIdx.x; t < 1024; t += TPB) hist[t] = 0;
    __syncthreads();
    int base = blockIdx.x * 4096;
    int pk[16], bk[16], rk[16];
#pragma unroll
    for (int k = 0; k < 16; k++) {
        int e = base + k * TPB + (int)threadIdx.x;
        bk[k] = -1;
        if (e < E) {
            int s = src[e], d = dst[e];
            int b = d >> SH;
            bk[k] = b;
            pk[k] = (s << SH) | (d & (BW - 1));
            rk[k] = atomicAdd(&hist[b], 1);
        }
    }
    __syncthreads();
    for (int t = threadIdx.x; t < nbuk; t += TPB) {
        int h = hist[t];
        hist[t] = h ? atomicAdd(&bu[t], h) : 0;
    }
    __syncthreads();
#pragma unroll
    for (int k = 0; k < 16; k++)
        if (bk[k] >= 0) ebuf[hist[bk[k]] + rk[k]] = pk[k];
}

// Fused: per-bucket histogram -> local scan -> off/dinv -> fill col.
__global__ void bucket_csr_kernel(const int* __restrict__ ebuf0, const int* __restrict__ ebuf1,
                                  const int* __restrict__ boff, const int* __restrict__ bcnt,
                                  int n, int E,
                                  int* __restrict__ off0, int* __restrict__ off1,
                                  float* __restrict__ dinv0, float* __restrict__ dinv1,
                                  int* __restrict__ col0, int* __restrict__ col1) {
    int g = blockIdx.y;
    int b = blockIdx.x;
    const int* ebuf = g ? ebuf1 : ebuf0;
    int* off = g ? off1 : off0;
    float* dinv = g ? dinv1 : dinv0;
    int* col = g ? col1 : col0;
    __shared__ int h[BW], nb[BW], nrank[BW];
    int tid = threadIdx.x;
    if (tid < BW) h[tid] = 0;
    __syncthreads();
    int s = boff[g * 1024 + b], e = s + bcnt[g * 1024 + b];
    for (int i = s + tid; i < e; i += TPB)
        atomicAdd(&h[ebuf[i] & (BW - 1)], 1);
    __syncthreads();
    if (tid < BW) {
        int v = h[tid];
        int x = v;
        for (int d = 1; d < BW; d <<= 1) {
            int u = __shfl_up(x, d, 64);
            if (tid >= d) x += u;
        }
        int base = s + x - v;  // exclusive
        nb[tid] = base;
        nrank[tid] = 0;
        int node = b * BW + tid;
        if (node < n) {
            off[node] = base;
            dinv[node] = rsqrtf((float)v + 1.0f);
        }
        if (node == 0) off[n] = E;
    }
    __syncthreads();
    for (int i = s + tid; i < e; i += TPB) {
        int p = ebuf[i];
        int lo = p & (BW - 1);
        int r = atomicAdd(&nrank[lo], 1);
        col[nb[lo] + r] = p >> SH;
    }
}

// ---------------- dense matmul: Y[n,COUT] = bf16( dinv[n] * (X @ W) ) ----------
// W staged in LDS (broadcast b128 reads, conflict-free); X streamed from global
// into registers (no X staging: kills the 74KB LDS block + 8-way staging conflicts).
// Thread tile: 4 nodes x 16 cols (64 fp32 accs in VGPRs).

template <int CIN, int COUT>
__global__ void matmul_kernel(const float* __restrict__ X0, const float* __restrict__ X1,
                              const float* __restrict__ W,
                              const float* __restrict__ dinv0, const float* __restrict__ dinv1,
                              u16* __restrict__ Y0, u16* __restrict__ Y1, int n) {
    int g = blockIdx.y;
    const float* X = g ? X1 : X0;
    const float* dinv = g ? dinv1 : dinv0;
    u16* Y = g ? Y1 : Y0;
    constexpr int CG = COUT / 16;    // col-groups per node (16 cols each)
    constexpr int SLOTS = 256 / CG;  // node slots per block
    constexpr int BN = SLOTS * 4;    // nodes per block
    constexpr int W4 = COUT / 4;     // float4s per W row
    __shared__ float Ws[CIN * COUT];

    for (int i = threadIdx.x; i < CIN * COUT / 4; i += 256)
        ((float4*)Ws)[i] = ((const float4*)W)[i];
    __syncthreads();

    int cg = threadIdx.x % CG;
    int slot = threadIdx.x / CG;
    int n0 = blockIdx.x * BN + slot * 4;
    int c4 = cg * 4;  // first float4-index of this thread's 16 cols
    const float4* Wr = (const float4*)Ws;

    float4 acc[4][4];
#pragma unroll
    for (int m = 0; m < 4; m++)
#pragma unroll
        for (int j = 0; j < 4; j++) acc[m][j] = make_float4(0.f, 0.f, 0.f, 0.f);

    for (int k0 = 0; k0 < CIN; k0 += 4) {
        float4 xv[4];
#pragma unroll
        for (int m = 0; m < 4; m++) {
            int node = n0 + m;
            xv[m] = (node < n) ? *(const float4*)&X[(size_t)node * CIN + k0]
                               : make_float4(0.f, 0.f, 0.f, 0.f);
        }
#pragma unroll
        for (int kk = 0; kk < 4; kk++) {
            float4 wv[4];
#pragma unroll
            for (int j = 0; j < 4; j++) wv[j] = Wr[(k0 + kk) * W4 + c4 + j];
#pragma unroll
            for (int m = 0; m < 4; m++) {
                float xs = ((const float*)&xv[m])[kk];
#pragma unroll
                for (int j = 0; j < 4; j++) {
                    acc[m][j].x += xs * wv[j].x;
                    acc[m][j].y += xs * wv[j].y;
                    acc[m][j].z += xs * wv[j].z;
                    acc[m][j].w += xs * wv[j].w;
                }
            }
        }
    }
#pragma unroll
    for (int m = 0; m < 4; m++) {
        int node = n0 + m;
        if (node < n) {
            float d = dinv[node];
#pragma unroll
            for (int j = 0; j < 4; j++) {
                ushort4 r;
                r.x = f_to_bf(acc[m][j].x * d);
                r.y = f_to_bf(acc[m][j].y * d);
                r.z = f_to_bf(acc[m][j].z * d);
                r.w = f_to_bf(acc[m][j].w * d);
                *(ushort4*)&Y[(size_t)node * COUT + (c4 + j) * 4] = r;
            }
        }
    }
}

// ---------------- GCN aggregation (gather over CSR-by-dst, bf16 payload) -------------
// HW pre-scaled by dinv_j (bf16). out[i,c] = act(dinv_i*(sum_j HW[j,c] + HW[i,c]) + b[c])
// SPLIT threads share one (node, channel-group); shuffle-butterfly combine.

__device__ __forceinline__ void facc(float4& a, float4 v) {
    a.x += v.x; a.y += v.y; a.z += v.z; a.w += v.w;
}

template <int C>
__device__ __forceinline__ float4 gather_sum(const u16* __restrict__ HW,
                                             const int* __restrict__ col,
                                             int c0, int ps, int pe) {
    float4 a0 = make_float4(0.f, 0.f, 0.f, 0.f);
    float4 a1 = a0, a2 = a0, a3 = a0;
    int p = ps;
    for (; p + 4 <= pe; p += 4) {
        int j0 = col[p], j1 = col[p + 1], j2 = col[p + 2], j3 = col[p + 3];
        facc(a0, bf4_to_f4(*(const ushort4*)&HW[(size_t)j0 * C + c0]));
        facc(a1, bf4_to_f4(*(const ushort4*)&HW[(size_t)j1 * C + c0]));
        facc(a2, bf4_to_f4(*(const ushort4*)&HW[(size_t)j2 * C + c0]));
        facc(a3, bf4_to_f4(*(const ushort4*)&HW[(size_t)j3 * C + c0]));
    }
    for (; p < pe; p++) {
        int j = col[p];
        facc(a0, bf4_to_f4(*(const ushort4*)&HW[(size_t)j * C + c0]));
    }
    facc(a0, a1); facc(a2, a3); facc(a0, a2);
    return a0;
}

__device__ __forceinline__ float4 shfl_xor4(float4 v, int mask, int width) {
    v.x = __shfl_xor(v.x, mask, width);
    v.y = __shfl_xor(v.y, mask, width);
    v.z = __shfl_xor(v.z, mask, width);
    v.w = __shfl_xor(v.w, mask, width);
    return v;
}

template <int C, int SPLIT, bool RELU>
__global__ void agg_kernel(const u16* __restrict__ HW0, const u16* __restrict__ HW1,
                           const int* __restrict__ off0, const int* __restrict__ off1,
                           const int* __restrict__ col0, const int* __restrict__ col1,
                           const float* __restrict__ dinv0, const float* __restrict__ dinv1,
                           const float* __restrict__ bias,
                           float* __restrict__ out0, float* __restrict__ out1, int n) {
    int g = blockIdx.y;
    const u16* HW = g ? HW1 : HW0;
    const int* off = g ? off1 : off0;
    const int* col = g ? col1 : col0;
    const float* dinv = g ? dinv1 : dinv0;
    float* outp = g ? out1 : out0;
    constexpr int CH = C / 4;
    constexpr int TPN = CH * SPLIT;
    int tid = blockIdx.x * blockDim.x + threadIdx.x;
    int node = tid / TPN;
    if (node >= n) return;
    int part = tid % TPN;
    int sp = part / CH;
    int c0 = (part % CH) * 4;
    int s = off[node], e = off[node + 1];
    int len = e - s;
    int chunk = (len + SPLIT - 1) / SPLIT;
    int ps = s + sp * chunk;
    int pe = min(ps + chunk, e);
    float4 r = gather_sum<C>(HW, col, c0, ps, pe);
#pragma unroll
    for (int m = CH; m < TPN; m <<= 1) facc(r, shfl_xor4(r, m, TPN));
    if (sp == 0) {
        float di = dinv[node];
        float4 self = bf4_to_f4(*(const ushort4*)&HW[(size_t)node * C + c0]);
        float4 b4 = *(const float4*)&bias[c0];
        float4 o;
        o.x = di * (r.x + self.x) + b4.x;
        o.y = di * (r.y + self.y) + b4.y;
        o.z = di * (r.z + self.z) + b4.z;
        o.w = di * (r.w + self.w) + b4.w;
        if (RELU) {
            o.x = fmaxf(o.x, 0.f); o.y = fmaxf(o.y, 0.f);
            o.z = fmaxf(o.z, 0.f); o.w = fmaxf(o.w, 0.f);
        }
        *(float4*)&outp[(size_t)node * C + c0] = o;
    }
}

// ---------------- attention pooling ----------------
// Small fixed grids: atomic traffic to the shared 128B accumulators stays ~2K ops.

__global__ void colsum_kernel(const float* __restrict__ H0, const float* __restrict__ H1,
                              int n, float* __restrict__ colsum) {
    int g = blockIdx.y;
    const float* H = g ? H1 : H0;
    int c = threadIdx.x % 16;
    int w = (blockIdx.x * blockDim.x + threadIdx.x) / 16;
    int stride = (gridDim.x * blockDim.x) / 16;
    float acc = 0.f;
    for (int node = w; node < n; node += stride) acc += H[(size_t)node * 16 + c];
    __shared__ float sdata[TPB];
    sdata[threadIdx.x] = acc;
    __syncthreads();
    if (threadIdx.x < 16) {
        float s = 0.f;
        for (int t = threadIdx.x; t < TPB; t += 16) s += sdata[t];
        atomicAdd(&colsum[g * 16 + threadIdx.x], s);
    }
}

__global__ void cvec_kernel(const float* __restrict__ colsum, const float* __restrict__ Wa,
                            float n_inv, float* __restrict__ cvec) {
    int g = blockIdx.x;
    int j = threadIdx.x;
    if (j < 16) {
        const float* cs = colsum + g * 16;
        float acc = 0.f;
        for (int i = 0; i < 16; i++) acc += (cs[i] * n_inv) * Wa[i * 16 + j];
        cvec[g * 16 + j] = tanhf(acc);
    }
}

__global__ void pool_kernel(const float* __restrict__ H0, const float* __restrict__ H1, int n,
                            const float* __restrict__ cvec, float* __restrict__ rep) {
    int g = blockIdx.y;
    const float* H = g ? H1 : H0;
    int c = threadIdx.x % 16;
    float cv = cvec[g * 16 + c];
    int w = (blockIdx.x * blockDim.x + threadIdx.x) / 16;
    int stride = (gridDim.x * blockDim.x) / 16;
    float acc = 0.f;
    for (int node = w; node < n; node += stride) {
        float x = H[(size_t)node * 16 + c];
        float p = x * cv;
        p += __shfl_xor(p, 1, 16);
        p += __shfl_xor(p, 2, 16);
        p += __shfl_xor(p, 4, 16);
        p += __shfl_xor(p, 8, 16);
        float s = 1.f / (1.f + __expf(-p));
        acc += s * x;
    }
    __shared__ float sdata[TPB];
    sdata[threadIdx.x] = acc;
    __syncthreads();
    if (threadIdx.x < 16) {
        float s = 0.f;
        for (int t = threadIdx.x; t < TPB; t += 16) s += sdata[t];
        atomicAdd(&rep[g * 16 + threadIdx.x], s);
    }
}

// ---------------- final tensor-network scoring ----------------

__global__ void final_kernel(const float* __restrict__ rep,
                             const float* __restrict__ Wt, const float* __restrict__ Wb,
                             const float* __restrict__ bt, const float* __restrict__ Wfc,
                             const float* __restrict__ bfc, const float* __restrict__ Wsc,
                             const float* __restrict__ bsc, float* __restrict__ out) {
    const float* e1 = rep;
    const float* e2 = rep + 16;
    __shared__ float scores[16], tvec[16], se1[16], se2[16];
    int t = threadIdx.x;
    if (t < 16) { se1[t] = e1[t]; se2[t] = e2[t]; }
    __syncthreads();
    if (t < 16) {
        float bil = 0.f;
        for (int i = 0; i < 16; i++) {
            float a = se1[i];
            for (int j = 0; j < 16; j++) bil += a * se2[j] * Wt[(i * 16 + j) * 16 + t];
        }
        float blk = 0.f;
        for (int m = 0; m < 16; m++)
            blk += Wb[t * 32 + m] * se1[m] + Wb[t * 32 + 16 + m] * se2[m];
        scores[t] = fmaxf(bil + blk + bt[t], 0.f);
    }
    __syncthreads();
    if (t < 16) {
        float acc = bfc[t];
        for (int k = 0; k < 16; k++) acc += scores[k] * Wfc[k * 16 + t];
        tvec[t] = tanhf(acc);
    }
    __syncthreads();
    if (t == 0) {
        float acc = bsc[0];
        for (int j = 0; j < 16; j++) acc += tvec[j] * Wsc[j];
        out[0] = 1.f / (1.f + __expf(-acc));
    }
}

// ---------------- launcher ----------------

extern "C" void kernel_launch(void* const* d_in, const int* in_sizes, int n_in,
                              void* d_out, int out_size, void* d_ws, size_t ws_size,
                              hipStream_t stream) {
    const float* X1 = (const float*)d_in[0];
    const float* X2 = (const float*)d_in[1];
    const int* edges1 = (const int*)d_in[2];
    const int* edges2 = (const int*)d_in[3];
    const float* W1 = (const float*)d_in[4];
    const float* b1 = (const float*)d_in[5];
    const float* W2 = (const float*)d_in[6];
    const float* b2 = (const float*)d_in[7];
    const float* W3 = (const float*)d_in[8];
    const float* b3 = (const float*)d_in[9];
    const float* Wa = (const float*)d_in[10];
    const float* Wt = (const float*)d_in[11];
    const float* Wb = (const float*)d_in[12];
    const float* bt = (const float*)d_in[13];
    const float* Wfc = (const float*)d_in[14];
    const float* bfc = (const float*)d_in[15];
    const float* Wsc = (const float*)d_in[16];
    const float* bsc = (const float*)d_in[17];
    float* out = (float*)d_out;

    const int N = in_sizes[0] / 96;
    const int E = in_sizes[2] / 2;
    const int NBUK = (N + BW - 1) / BW;  // buckets (must be <= 1024)

    // workspace layout (256B aligned chunks)
    char* ws = (char*)d_ws;
    size_t o = 0;
    auto alloc = [&](size_t bytes) {
        void* p = ws + o;
        o += (bytes + 255) & ~(size_t)255;
        return p;
    };
    // zero region: bcnt(2*1024 int) then small(96 float) — contiguous, one memset
    int* bcnt = (int*)alloc((size_t)2 * 1024 * 4);
    float* small = (float*)alloc(96 * 4);  // colsum[2*16] cvec[2*16] rep[2*16]
    float* colsum = small;
    float* cvec = small + 32;
    float* rep = small + 64;
    int* boff = (int*)alloc((size_t)2 * 1024 * 4);
    int* bcur = (int*)alloc((size_t)2 * 1024 * 4);
    int* off0 = (int*)alloc((size_t)(N + 1) * 4);
    int* off1 = (int*)alloc((size_t)(N + 1) * 4);
    int* col0 = (int*)alloc((size_t)E * 4);
    int* col1 = (int*)alloc((size_t)E * 4);
    float* dinv0 = (float*)alloc((size_t)N * 4);
    float* dinv1 = (float*)alloc((size_t)N * 4);
    int* ebuf0 = (int*)alloc((size_t)E * 4);
    int* ebuf1 = (int*)alloc((size_t)E * 4);
    u16* hwb0 = (u16*)alloc((size_t)N * 64 * 2);   // bf16 gather payload
    u16* hwb1 = (u16*)alloc((size_t)N * 64 * 2);
    float* bufB0 = (float*)alloc((size_t)N * 64 * 4);  // fp32 agg outputs
    float* bufB1 = (float*)alloc((size_t)N * 64 * 4);

    const int gB1 = (E + 8191) / 8192;
    const int gB2 = (E + 4095) / 4096;
    const int g16 = ((size_t)N * 16 + TPB - 1) / TPB;  // all aggs run 16 threads/node

    hipMemsetAsync(bcnt, 0, (size_t)2 * 1024 * 4 + 96 * 4, stream);

    // bucketed CSR build (both graphs per dispatch)
    bucket_count_kernel<<<dim3(gB1, 2), TPB, 0, stream>>>(edges1 + E, edges2 + E, E, bcnt, NBUK);
    bucket_scan_kernel<<<2, 1024, 0, stream>>>(bcnt, NBUK, boff, bcur);
    bucket_scatter_kernel<<<dim3(gB2, 2), TPB, 0, stream>>>(edges1, edges2, E, bcur, ebuf0, ebuf1, NBUK);
    bucket_csr_kernel<<<dim3(NBUK, 2), TPB, 0, stream>>>(ebuf0, ebuf1, boff, bcnt, N, E,
                                                         off0, off1, dinv0, dinv1, col0, col1);

    // layer 1: 96 -> 64 (BN=256), agg + relu (SPLIT=1: 16 threads/node)
    matmul_kernel<96, 64><<<dim3((N + 255) / 256, 2), TPB, 0, stream>>>(X1, X2, W1, dinv0, dinv1, hwb0, hwb1, N);
    agg_kernel<64, 1, true><<<dim3(g16, 2), TPB, 0, stream>>>(
        hwb0, hwb1, off0, off1, col0, col1, dinv0, dinv1, b1, bufB0, bufB1, N);
    // layer 2: 64 -> 32 (BN=512), agg + relu (SPLIT=2)
    matmul_kernel<64, 32><<<dim3((N + 511) / 512, 2), TPB, 0, stream>>>(bufB0, bufB1, W2, dinv0, dinv1, hwb0, hwb1, N);
    agg_kernel<32, 2, true><<<dim3(g16, 2), TPB, 0, stream>>>(
        hwb0, hwb1, off0, off1, col0, col1, dinv0, dinv1, b2, bufB0, bufB1, N);
    // layer 3: 32 -> 16 (BN=1024), agg, no relu (SPLIT=4)
    matmul_kernel<32, 16><<<dim3((N + 1023) / 1024, 2), TPB, 0, stream>>>(bufB0, bufB1, W3, dinv0, dinv1, hwb0, hwb1, N);
    agg_kernel<16, 4, false><<<dim3(g16, 2), TPB, 0, stream>>>(
        hwb0, hwb1, off0, off1, col0, col1, dinv0, dinv1, b3, bufB0, bufB1, N);

    // attention pooling (small grids: minimal same-line atomic traffic)
    colsum_kernel<<<dim3(64, 2), TPB, 0, stream>>>(bufB0, bufB1, N, colsum);
    cvec_kernel<<<2, 64, 0, stream>>>(colsum, Wa, 1.0f / (float)N, cvec);
    pool_kernel<<<dim3(64, 2), TPB, 0, stream>>>(bufB0, bufB1, N, cvec, rep);

    final_kernel<<<1, 64, 0, stream>>>(rep, Wt, Wb, bt, Wfc, bfc, Wsc, bsc, out);
}

// Round 10
// 292.980 us; speedup vs baseline: 1.2161x; 1.2161x over previous
//
#include <hip/hip_runtime.h>
#include <hip/hip_bf16.h>

#define TPB 256
#define SH 6
#define BW 64  // nodes per bucket = 1<<SH; NBUK must be <= 1024 (N <= 65536)

typedef unsigned short u16;
typedef __attribute__((ext_vector_type(8))) __bf16 bf16x8;  // MFMA A/B frag (4 VGPRs)
typedef __attribute__((ext_vector_type(4))) float f32x4;    // MFMA C/D frag

// bf16 helpers: payload stored as bf16 (halves gather BW), accumulate in fp32.
__device__ __forceinline__ u16 f_to_bf(float f) {
    unsigned u = __float_as_uint(f);
    return (u16)((u + 0x7fff + ((u >> 16) & 1)) >> 16);  // RNE
}
__device__ __forceinline__ float4 bf4_to_f4(ushort4 v) {
    float4 r;
    r.x = __uint_as_float((unsigned)v.x << 16);
    r.y = __uint_as_float((unsigned)v.y << 16);
    r.z = __uint_as_float((unsigned)v.z << 16);
    r.w = __uint_as_float((unsigned)v.w << 16);
    return r;
}

// ---------------- bucketed CSR build ----------------

__global__ void bucket_count_kernel(const int* __restrict__ dst0, const int* __restrict__ dst1,
                                    int E, int* __restrict__ bcnt, int nbuk) {
    const int* dst = blockIdx.y ? dst1 : dst0;
    int* bc = bcnt + blockIdx.y * 1024;
    __shared__ int hist[1024];
    for (int t = threadIdx.x; t < 1024; t += TPB) hist[t] = 0;
    __syncthreads();
    int base = blockIdx.x * 8192;
    int end = min(base + 8192, E);
    for (int e = base + (int)threadIdx.x; e < end; e += TPB)
        atomicAdd(&hist[dst[e] >> SH], 1);
    __syncthreads();
    for (int t = threadIdx.x; t < nbuk; t += TPB) {
        int h = hist[t];
        if (h) atomicAdd(&bc[t], h);
    }
}

__global__ void bucket_scan_kernel(const int* __restrict__ bcnt, int nbuk,
                                   int* __restrict__ boff, int* __restrict__ bcur) {
    int g = blockIdx.x;
    const int* bc = bcnt + g * 1024;
    int* bo = boff + g * 1024;
    int* bu = bcur + g * 1024;
    __shared__ int s[1024];
    int t = threadIdx.x;
    int v = (t < nbuk) ? bc[t] : 0;
    s[t] = v;
    __syncthreads();
    for (int st = 1; st < 1024; st <<= 1) {
        int u = (t >= st) ? s[t - st] : 0;
        __syncthreads();
        s[t] += u;
        __syncthreads();
    }
    if (t < nbuk) { int e = s[t] - v; bo[t] = e; bu[t] = e; }
}

__global__ void bucket_scatter_kernel(const int* __restrict__ e0, const int* __restrict__ e1,
                                      int E, int* __restrict__ bcur,
                                      int* __restrict__ ebuf0, int* __restrict__ ebuf1, int nbuk) {
    int g = blockIdx.y;
    const int* src = g ? e1 : e0;
    const int* dst = src + E;
    int* ebuf = g ? ebuf1 : ebuf0;
    int* bu = bcur + g * 1024;
    __shared__ int hist[1024];
    for (int t = threadIdx.x; t < 1024; t += TPB) hist[t] = 0;
    __syncthreads();
    int base = blockIdx.x * 4096;
    int pk[16], bk[16], rk[16];
#pragma unroll
    for (int k = 0; k < 16; k++) {
        int e = base + k * TPB + (int)threadIdx.x;
        bk[k] = -1;
        if (e < E) {
            int s = src[e], d = dst[e];
            int b = d >> SH;
            bk[k] = b;
            pk[k] = (s << SH) | (d & (BW - 1));
            rk[k] = atomicAdd(&hist[b], 1);
        }
    }
    __syncthreads();
    for (int t = threadIdx.x; t < nbuk; t += TPB) {
        int h = hist[t];
        hist[t] = h ? atomicAdd(&bu[t], h) : 0;
    }
    __syncthreads();
#pragma unroll
    for (int k = 0; k < 16; k++)
        if (bk[k] >= 0) ebuf[hist[bk[k]] + rk[k]] = pk[k];
}

// Fused: per-bucket histogram -> local scan -> off/dinv -> fill col.
__global__ void bucket_csr_kernel(const int* __restrict__ ebuf0, const int* __restrict__ ebuf1,
                                  const int* __restrict__ boff, const int* __restrict__ bcnt,
                                  int n, int E,
                                  int* __restrict__ off0, int* __restrict__ off1,
                                  float* __restrict__ dinv0, float* __restrict__ dinv1,
                                  int* __restrict__ col0, int* __restrict__ col1) {
    int g = blockIdx.y;
    int b = blockIdx.x;
    const int* ebuf = g ? ebuf1 : ebuf0;
    int* off = g ? off1 : off0;
    float* dinv = g ? dinv1 : dinv0;
    int* col = g ? col1 : col0;
    __shared__ int h[BW], nb[BW], nrank[BW];
    int tid = threadIdx.x;
    if (tid < BW) h[tid] = 0;
    __syncthreads();
    int s = boff[g * 1024 + b], e = s + bcnt[g * 1024 + b];
    for (int i = s + tid; i < e; i += TPB)
        atomicAdd(&h[ebuf[i] & (BW - 1)], 1);
    __syncthreads();
    if (tid < BW) {
        int v = h[tid];
        int x = v;
        for (int d = 1; d < BW; d <<= 1) {
            int u = __shfl_up(x, d, 64);
            if (tid >= d) x += u;
        }
        int base = s + x - v;  // exclusive
        nb[tid] = base;
        nrank[tid] = 0;
        int node = b * BW + tid;
        if (node < n) {
            off[node] = base;
            dinv[node] = rsqrtf((float)v + 1.0f);
        }
        if (node == 0) off[n] = E;
    }
    __syncthreads();
    for (int i = s + tid; i < e; i += TPB) {
        int p = ebuf[i];
        int lo = p & (BW - 1);
        int r = atomicAdd(&nrank[lo], 1);
        col[nb[lo] + r] = p >> SH;
    }
}

// ---------------- dense matmul via MFMA: Y = bf16( dinv[n] * (X @ W) ) ----------
// Block = 4 waves = 64 nodes. X-tile and W^T staged in LDS as bf16 (coalesced fp32
// reads, RNE convert). Each wave: 16 nodes x COUT cols via mfma_f32_16x16x32_bf16.
// Frag layouts (m89/m91/m120-verified): A[m=lane&15][k=quad*8+j]; B[n=lane&15][k=quad*8+j]
// (so W stored transposed [n][k]); D: col=lane&15, row=quad*4+reg.

template <int CIN, int COUT>
__global__ void matmul_kernel(const float* __restrict__ X0, const float* __restrict__ X1,
                              const float* __restrict__ W,
                              const float* __restrict__ dinv0, const float* __restrict__ dinv1,
                              u16* __restrict__ Y0, u16* __restrict__ Y1, int n) {
    constexpr int CINP = CIN + 8;   // padded row (bf16 elems): 16B-aligned, bank-spread
    constexpr int NT = COUT / 16;   // n-tiles per wave
    constexpr int KT = CIN / 32;    // K steps
    __shared__ u16 Xs[64 * CINP];
    __shared__ u16 Wt[COUT * CINP];

    int g = blockIdx.y;
    const float* X = g ? X1 : X0;
    const float* dinv = g ? dinv1 : dinv0;
    u16* Y = g ? Y1 : Y0;
    int nb0 = blockIdx.x * 64;

    // stage X tile (fp32 coalesced -> bf16 LDS)
    for (int i = threadIdx.x; i < 64 * (CIN / 4); i += TPB) {
        int nn = i / (CIN / 4), kc = i % (CIN / 4);
        float4 v = make_float4(0.f, 0.f, 0.f, 0.f);
        if (nb0 + nn < n) v = *(const float4*)&X[(size_t)(nb0 + nn) * CIN + 4 * kc];
        ushort4 b;
        b.x = f_to_bf(v.x); b.y = f_to_bf(v.y); b.z = f_to_bf(v.z); b.w = f_to_bf(v.w);
        *(ushort4*)&Xs[nn * CINP + 4 * kc] = b;
    }
    // stage W transposed (fp32 [k][n] coalesced -> bf16 LDS [n][k])
    for (int i = threadIdx.x; i < CIN * (COUT / 4); i += TPB) {
        int k = i / (COUT / 4), nc4 = i % (COUT / 4);
        float4 v = *(const float4*)&W[(size_t)k * COUT + 4 * nc4];
        Wt[(4 * nc4 + 0) * CINP + k] = f_to_bf(v.x);
        Wt[(4 * nc4 + 1) * CINP + k] = f_to_bf(v.y);
        Wt[(4 * nc4 + 2) * CINP + k] = f_to_bf(v.z);
        Wt[(4 * nc4 + 3) * CINP + k] = f_to_bf(v.w);
    }
    __syncthreads();

    int lane = threadIdx.x & 63;
    int w = threadIdx.x >> 6;      // wave id: nodes nb0 + w*16 .. +15
    int m = lane & 15;
    int quad = lane >> 4;

    f32x4 acc[NT];
#pragma unroll
    for (int t = 0; t < NT; t++) acc[t] = (f32x4){0.f, 0.f, 0.f, 0.f};

#pragma unroll
    for (int kt = 0; kt < KT; kt++) {
        int k0 = kt * 32 + quad * 8;
        bf16x8 a = *(const bf16x8*)&Xs[(w * 16 + m) * CINP + k0];
#pragma unroll
        for (int t = 0; t < NT; t++) {
            bf16x8 b = *(const bf16x8*)&Wt[(t * 16 + m) * CINP + k0];
            acc[t] = __builtin_amdgcn_mfma_f32_16x16x32_bf16(a, b, acc[t], 0, 0, 0);
        }
    }

#pragma unroll
    for (int r = 0; r < 4; r++) {
        int node = nb0 + w * 16 + quad * 4 + r;
        if (node < n) {
            float d = dinv[node];
#pragma unroll
            for (int t = 0; t < NT; t++)
                Y[(size_t)node * COUT + t * 16 + m] = f_to_bf(acc[t][r] * d);
        }
    }
}

// ---------------- GCN aggregation (gather over CSR-by-dst, bf16 payload) -------------
// HW pre-scaled by dinv_j (bf16). out[i,c] = act(dinv_i*(sum_j HW[j,c] + HW[i,c]) + b[c])
// SPLIT threads share one (node, channel-group); shuffle-butterfly combine.

__device__ __forceinline__ void facc(float4& a, float4 v) {
    a.x += v.x; a.y += v.y; a.z += v.z; a.w += v.w;
}

template <int C>
__device__ __forceinline__ float4 gather_sum(const u16* __restrict__ HW,
                                             const int* __restrict__ col,
                                             int c0, int ps, int pe) {
    float4 a0 = make_float4(0.f, 0.f, 0.f, 0.f);
    float4 a1 = a0, a2 = a0, a3 = a0;
    int p = ps;
    for (; p + 4 <= pe; p += 4) {
        int j0 = col[p], j1 = col[p + 1], j2 = col[p + 2], j3 = col[p + 3];
        facc(a0, bf4_to_f4(*(const ushort4*)&HW[(size_t)j0 * C + c0]));
        facc(a1, bf4_to_f4(*(const ushort4*)&HW[(size_t)j1 * C + c0]));
        facc(a2, bf4_to_f4(*(const ushort4*)&HW[(size_t)j2 * C + c0]));
        facc(a3, bf4_to_f4(*(const ushort4*)&HW[(size_t)j3 * C + c0]));
    }
    for (; p < pe; p++) {
        int j = col[p];
        facc(a0, bf4_to_f4(*(const ushort4*)&HW[(size_t)j * C + c0]));
    }
    facc(a0, a1); facc(a2, a3); facc(a0, a2);
    return a0;
}

__device__ __forceinline__ float4 shfl_xor4(float4 v, int mask, int width) {
    v.x = __shfl_xor(v.x, mask, width);
    v.y = __shfl_xor(v.y, mask, width);
    v.z = __shfl_xor(v.z, mask, width);
    v.w = __shfl_xor(v.w, mask, width);
    return v;
}

template <int C, int SPLIT, bool RELU>
__global__ void agg_kernel(const u16* __restrict__ HW0, const u16* __restrict__ HW1,
                           const int* __restrict__ off0, const int* __restrict__ off1,
                           const int* __restrict__ col0, const int* __restrict__ col1,
                           const float* __restrict__ dinv0, const float* __restrict__ dinv1,
                           const float* __restrict__ bias,
                           float* __restrict__ out0, float* __restrict__ out1, int n) {
    int g = blockIdx.y;
    const u16* HW = g ? HW1 : HW0;
    const int* off = g ? off1 : off0;
    const int* col = g ? col1 : col0;
    const float* dinv = g ? dinv1 : dinv0;
    float* outp = g ? out1 : out0;
    constexpr int CH = C / 4;
    constexpr int TPN = CH * SPLIT;
    int tid = blockIdx.x * blockDim.x + threadIdx.x;
    int node = tid / TPN;
    if (node >= n) return;
    int part = tid % TPN;
    int sp = part / CH;
    int c0 = (part % CH) * 4;
    int s = off[node], e = off[node + 1];
    int len = e - s;
    int chunk = (len + SPLIT - 1) / SPLIT;
    int ps = s + sp * chunk;
    int pe = min(ps + chunk, e);
    float4 r = gather_sum<C>(HW, col, c0, ps, pe);
#pragma unroll
    for (int m = CH; m < TPN; m <<= 1) facc(r, shfl_xor4(r, m, TPN));
    if (sp == 0) {
        float di = dinv[node];
        float4 self = bf4_to_f4(*(const ushort4*)&HW[(size_t)node * C + c0]);
        float4 b4 = *(const float4*)&bias[c0];
        float4 o;
        o.x = di * (r.x + self.x) + b4.x;
        o.y = di * (r.y + self.y) + b4.y;
        o.z = di * (r.z + self.z) + b4.z;
        o.w = di * (r.w + self.w) + b4.w;
        if (RELU) {
            o.x = fmaxf(o.x, 0.f); o.y = fmaxf(o.y, 0.f);
            o.z = fmaxf(o.z, 0.f); o.w = fmaxf(o.w, 0.f);
        }
        *(float4*)&outp[(size_t)node * C + c0] = o;
    }
}

// ---------------- attention pooling ----------------
// Small fixed grids: atomic traffic to the shared 128B accumulators stays ~2K ops.

__global__ void colsum_kernel(const float* __restrict__ H0, const float* __restrict__ H1,
                              int n, float* __restrict__ colsum) {
    int g = blockIdx.y;
    const float* H = g ? H1 : H0;
    int c = threadIdx.x % 16;
    int w = (blockIdx.x * blockDim.x + threadIdx.x) / 16;
    int stride = (gridDim.x * blockDim.x) / 16;
    float acc = 0.f;
    for (int node = w; node < n; node += stride) acc += H[(size_t)node * 16 + c];
    __shared__ float sdata[TPB];
    sdata[threadIdx.x] = acc;
    __syncthreads();
    if (threadIdx.x < 16) {
        float s = 0.f;
        for (int t = threadIdx.x; t < TPB; t += 16) s += sdata[t];
        atomicAdd(&colsum[g * 16 + threadIdx.x], s);
    }
}

__global__ void cvec_kernel(const float* __restrict__ colsum, const float* __restrict__ Wa,
                            float n_inv, float* __restrict__ cvec) {
    int g = blockIdx.x;
    int j = threadIdx.x;
    if (j < 16) {
        const float* cs = colsum + g * 16;
        float acc = 0.f;
        for (int i = 0; i < 16; i++) acc += (cs[i] * n_inv) * Wa[i * 16 + j];
        cvec[g * 16 + j] = tanhf(acc);
    }
}

__global__ void pool_kernel(const float* __restrict__ H0, const float* __restrict__ H1, int n,
                            const float* __restrict__ cvec, float* __restrict__ rep) {
    int g = blockIdx.y;
    const float* H = g ? H1 : H0;
    int c = threadIdx.x % 16;
    float cv = cvec[g * 16 + c];
    int w = (blockIdx.x * blockDim.x + threadIdx.x) / 16;
    int stride = (gridDim.x * blockDim.x) / 16;
    float acc = 0.f;
    for (int node = w; node < n; node += stride) {
        float x = H[(size_t)node * 16 + c];
        float p = x * cv;
        p += __shfl_xor(p, 1, 16);
        p += __shfl_xor(p, 2, 16);
        p += __shfl_xor(p, 4, 16);
        p += __shfl_xor(p, 8, 16);
        float s = 1.f / (1.f + __expf(-p));
        acc += s * x;
    }
    __shared__ float sdata[TPB];
    sdata[threadIdx.x] = acc;
    __syncthreads();
    if (threadIdx.x < 16) {
        float s = 0.f;
        for (int t = threadIdx.x; t < TPB; t += 16) s += sdata[t];
        atomicAdd(&rep[g * 16 + threadIdx.x], s);
    }
}

// ---------------- final tensor-network scoring ----------------

__global__ void final_kernel(const float* __restrict__ rep,
                             const float* __restrict__ Wt, const float* __restrict__ Wb,
                             const float* __restrict__ bt, const float* __restrict__ Wfc,
                             const float* __restrict__ bfc, const float* __restrict__ Wsc,
                             const float* __restrict__ bsc, float* __restrict__ out) {
    const float* e1 = rep;
    const float* e2 = rep + 16;
    __shared__ float scores[16], tvec[16], se1[16], se2[16];
    int t = threadIdx.x;
    if (t < 16) { se1[t] = e1[t]; se2[t] = e2[t]; }
    __syncthreads();
    if (t < 16) {
        float bil = 0.f;
        for (int i = 0; i < 16; i++) {
            float a = se1[i];
            for (int j = 0; j < 16; j++) bil += a * se2[j] * Wt[(i * 16 + j) * 16 + t];
        }
        float blk = 0.f;
        for (int m = 0; m < 16; m++)
            blk += Wb[t * 32 + m] * se1[m] + Wb[t * 32 + 16 + m] * se2[m];
        scores[t] = fmaxf(bil + blk + bt[t], 0.f);
    }
    __syncthreads();
    if (t < 16) {
        float acc = bfc[t];
        for (int k = 0; k < 16; k++) acc += scores[k] * Wfc[k * 16 + t];
        tvec[t] = tanhf(acc);
    }
    __syncthreads();
    if (t == 0) {
        float acc = bsc[0];
        for (int j = 0; j < 16; j++) acc += tvec[j] * Wsc[j];
        out[0] = 1.f / (1.f + __expf(-acc));
    }
}

// ---------------- launcher ----------------

extern "C" void kernel_launch(void* const* d_in, const int* in_sizes, int n_in,
                              void* d_out, int out_size, void* d_ws, size_t ws_size,
                              hipStream_t stream) {
    const float* X1 = (const float*)d_in[0];
    const float* X2 = (const float*)d_in[1];
    const int* edges1 = (const int*)d_in[2];
    const int* edges2 = (const int*)d_in[3];
    const float* W1 = (const float*)d_in[4];
    const float* b1 = (const float*)d_in[5];
    const float* W2 = (const float*)d_in[6];
    const float* b2 = (const float*)d_in[7];
    const float* W3 = (const float*)d_in[8];
    const float* b3 = (const float*)d_in[9];
    const float* Wa = (const float*)d_in[10];
    const float* Wt = (const float*)d_in[11];
    const float* Wb = (const float*)d_in[12];
    const float* bt = (const float*)d_in[13];
    const float* Wfc = (const float*)d_in[14];
    const float* bfc = (const float*)d_in[15];
    const float* Wsc = (const float*)d_in[16];
    const float* bsc = (const float*)d_in[17];
    float* out = (float*)d_out;

    const int N = in_sizes[0] / 96;
    const int E = in_sizes[2] / 2;
    const int NBUK = (N + BW - 1) / BW;  // buckets (must be <= 1024)

    // workspace layout (256B aligned chunks)
    char* ws = (char*)d_ws;
    size_t o = 0;
    auto alloc = [&](size_t bytes) {
        void* p = ws + o;
        o += (bytes + 255) & ~(size_t)255;
        return p;
    };
    // zero region: bcnt(2*1024 int) then small(96 float) — contiguous, one memset
    int* bcnt = (int*)alloc((size_t)2 * 1024 * 4);
    float* small = (float*)alloc(96 * 4);  // colsum[2*16] cvec[2*16] rep[2*16]
    float* colsum = small;
    float* cvec = small + 32;
    float* rep = small + 64;
    int* boff = (int*)alloc((size_t)2 * 1024 * 4);
    int* bcur = (int*)alloc((size_t)2 * 1024 * 4);
    int* off0 = (int*)alloc((size_t)(N + 1) * 4);
    int* off1 = (int*)alloc((size_t)(N + 1) * 4);
    int* col0 = (int*)alloc((size_t)E * 4);
    int* col1 = (int*)alloc((size_t)E * 4);
    float* dinv0 = (float*)alloc((size_t)N * 4);
    float* dinv1 = (float*)alloc((size_t)N * 4);
    int* ebuf0 = (int*)alloc((size_t)E * 4);
    int* ebuf1 = (int*)alloc((size_t)E * 4);
    u16* hwb0 = (u16*)alloc((size_t)N * 64 * 2);   // bf16 gather payload
    u16* hwb1 = (u16*)alloc((size_t)N * 64 * 2);
    float* bufB0 = (float*)alloc((size_t)N * 64 * 4);  // fp32 agg outputs
    float* bufB1 = (float*)alloc((size_t)N * 64 * 4);

    const int gB1 = (E + 8191) / 8192;
    const int gB2 = (E + 4095) / 4096;
    const int g16 = ((size_t)N * 16 + TPB - 1) / TPB;  // all aggs run 16 threads/node
    const int gMM = (N + 63) / 64;                     // MFMA matmul: 64 nodes/block

    hipMemsetAsync(bcnt, 0, (size_t)2 * 1024 * 4 + 96 * 4, stream);

    // bucketed CSR build (both graphs per dispatch)
    bucket_count_kernel<<<dim3(gB1, 2), TPB, 0, stream>>>(edges1 + E, edges2 + E, E, bcnt, NBUK);
    bucket_scan_kernel<<<2, 1024, 0, stream>>>(bcnt, NBUK, boff, bcur);
    bucket_scatter_kernel<<<dim3(gB2, 2), TPB, 0, stream>>>(edges1, edges2, E, bcur, ebuf0, ebuf1, NBUK);
    bucket_csr_kernel<<<dim3(NBUK, 2), TPB, 0, stream>>>(ebuf0, ebuf1, boff, bcnt, N, E,
                                                         off0, off1, dinv0, dinv1, col0, col1);

    // layer 1: 96 -> 64 (MFMA), agg + relu (SPLIT=1: 16 threads/node)
    matmul_kernel<96, 64><<<dim3(gMM, 2), TPB, 0, stream>>>(X1, X2, W1, dinv0, dinv1, hwb0, hwb1, N);
    agg_kernel<64, 1, true><<<dim3(g16, 2), TPB, 0, stream>>>(
        hwb0, hwb1, off0, off1, col0, col1, dinv0, dinv1, b1, bufB0, bufB1, N);
    // layer 2: 64 -> 32 (MFMA), agg + relu (SPLIT=2)
    matmul_kernel<64, 32><<<dim3(gMM, 2), TPB, 0, stream>>>(bufB0, bufB1, W2, dinv0, dinv1, hwb0, hwb1, N);
    agg_kernel<32, 2, true><<<dim3(g16, 2), TPB, 0, stream>>>(
        hwb0, hwb1, off0, off1, col0, col1, dinv0, dinv1, b2, bufB0, bufB1, N);
    // layer 3: 32 -> 16 (MFMA), agg, no relu (SPLIT=4)
    matmul_kernel<32, 16><<<dim3(gMM, 2), TPB, 0, stream>>>(bufB0, bufB1, W3, dinv0, dinv1, hwb0, hwb1, N);
    agg_kernel<16, 4, false><<<dim3(g16, 2), TPB, 0, stream>>>(
        hwb0, hwb1, off0, off1, col0, col1, dinv0, dinv1, b3, bufB0, bufB1, N);

    // attention pooling (small grids: minimal same-line atomic traffic)
    colsum_kernel<<<dim3(64, 2), TPB, 0, stream>>>(bufB0, bufB1, N, colsum);
    cvec_kernel<<<2, 64, 0, stream>>>(colsum, Wa, 1.0f / (float)N, cvec);
    pool_kernel<<<dim3(64, 2), TPB, 0, stream>>>(bufB0, bufB1, N, cvec, rep);

    final_kernel<<<1, 64, 0, stream>>>(rep, Wt, Wb, bt, Wfc, bfc, Wsc, bsc, out);
}